// Round 2
// baseline (744.797 us; speedup 1.0000x reference)
//
#include <hip/hip_runtime.h>
#include <hip/hip_bf16.h>

#define DEVINL __device__ __forceinline__

constexpr int Bg      = 64;
constexpr int Nn      = 512;
constexpr int Vv      = 64;
constexpr int E_PER   = 16384;
constexpr int IND     = 128;
constexpr int Hd      = 256;
constexpr int OUTD    = 10;
constexpr int TOTAL_N = Bg * Nn;    // 32768
constexpr int NE      = Bg * E_PER; // 1048576

// ---------------- zero int buffer ----------------
__global__ void k_zero_i32(int* p, int n) {
    int i = blockIdx.x * blockDim.x + threadIdx.x;
    if (i < n) p[i] = 0;
}

// ---------------- edge count ----------------
__global__ void k_count(const int* __restrict__ edst, int* __restrict__ cnt) {
    int e = blockIdx.x * blockDim.x + threadIdx.x;
    if (e < NE) atomicAdd(&cnt[edst[e]], 1);
}

// ---------------- exclusive scan over 32768 counts (single block, 1024 thr) ----
__global__ __launch_bounds__(1024) void k_scan(const int* __restrict__ cnt,
                                               int* __restrict__ rowstart,
                                               int* __restrict__ cursor,
                                               float* __restrict__ dinv) {
    __shared__ int part[1024];
    int t = threadIdx.x;
    int base = t * 32;
    int local[32];
    int s = 0;
#pragma unroll
    for (int i = 0; i < 32; i++) { local[i] = cnt[base + i]; s += local[i]; }
    part[t] = s;
    __syncthreads();
    // Hillis-Steele inclusive scan
    for (int off = 1; off < 1024; off <<= 1) {
        int v = (t >= off) ? part[t - off] : 0;
        __syncthreads();
        part[t] += v;
        __syncthreads();
    }
    int run = part[t] - s; // exclusive prefix
#pragma unroll
    for (int i = 0; i < 32; i++) {
        int idx = base + i;
        rowstart[idx] = run;
        cursor[idx]   = run;
        int c = local[i];
        dinv[idx] = rsqrtf((float)(c + 1));
        run += c;
    }
    if (t == 0) rowstart[TOTAL_N] = NE;
}

// ---------------- scatter edges into CSR ----------------
__global__ void k_scatter(const int* __restrict__ esrc, const int* __restrict__ edst,
                          int* __restrict__ cursor, const float* __restrict__ dinv,
                          int* __restrict__ csr_src, float* __restrict__ csr_coef) {
    int e = blockIdx.x * blockDim.x + threadIdx.x;
    if (e >= NE) return;
    int s = esrc[e], d = edst[e];
    int pos = atomicAdd(&cursor[d], 1);
    csr_src[pos]  = s;
    csr_coef[pos] = dinv[s] * dinv[d];
}

// ---------------- tiled GEMM: C[M,Nc] = A[M,K] @ W[K,Nc] (+bias)(+relu) ----
// BM=BN=64, BK=16, 256 threads, 4x4 micro-tile. Requires M%64==0, Nc%64==0, K%16==0.
__global__ __launch_bounds__(256) void k_gemm(const float* __restrict__ A,
                                              const float* __restrict__ W,
                                              const float* __restrict__ bias,
                                              float* __restrict__ C,
                                              int M, int K, int Nc, int relu) {
    __shared__ float As[16][64];
    __shared__ float Ws[16][64 + 1];
    int tid = threadIdx.x;
    int tx = tid & 15, ty = tid >> 4;
    int row0 = blockIdx.y * 64, col0 = blockIdx.x * 64;
    float acc[4][4] = {};
    for (int k0 = 0; k0 < K; k0 += 16) {
        {
            int m  = tid >> 2;
            int kq = (tid & 3) * 4;
            const float* ap = A + (size_t)(row0 + m) * K + k0 + kq;
            float4 av = *(const float4*)ap;
            As[kq + 0][m] = av.x;
            As[kq + 1][m] = av.y;
            As[kq + 2][m] = av.z;
            As[kq + 3][m] = av.w;
        }
        {
            int n = tid & 63;
            int kb = (tid >> 6) * 4;
#pragma unroll
            for (int i = 0; i < 4; i++) {
                int kk = kb + i;
                Ws[kk][n] = W[(size_t)(k0 + kk) * Nc + col0 + n];
            }
        }
        __syncthreads();
#pragma unroll
        for (int kk = 0; kk < 16; kk++) {
            float a[4], b[4];
#pragma unroll
            for (int i = 0; i < 4; i++) a[i] = As[kk][ty * 4 + i];
#pragma unroll
            for (int j = 0; j < 4; j++) b[j] = Ws[kk][tx * 4 + j];
#pragma unroll
            for (int i = 0; i < 4; i++)
#pragma unroll
                for (int j = 0; j < 4; j++) acc[i][j] += a[i] * b[j];
        }
        __syncthreads();
    }
#pragma unroll
    for (int i = 0; i < 4; i++) {
#pragma unroll
        for (int j = 0; j < 4; j++) {
            int col = col0 + tx * 4 + j;
            float v = acc[i][j];
            if (bias) v += bias[col];
            if (relu) v = fmaxf(v, 0.f);
            C[(size_t)(row0 + ty * 4 + i) * Nc + col] = v;
        }
    }
}

// ---------------- GCN aggregation: g = relu(selfloop + sum_e coef*hw[src] + b_gcn) ----
__global__ __launch_bounds__(256) void k_agg(const float* __restrict__ hw,
                                             const int* __restrict__ rowstart,
                                             const int* __restrict__ csr_src,
                                             const float* __restrict__ csr_coef,
                                             const float* __restrict__ dinv,
                                             const float* __restrict__ b_gcn,
                                             float* __restrict__ g) {
    __shared__ int   lsrc[256];
    __shared__ float lcoef[256];
    int node = blockIdx.x;
    int ch = threadIdx.x;
    float di = dinv[node];
    float acc = hw[(size_t)node * Hd + ch] * di * di; // self-loop: hw/deg
    int rs0 = rowstart[node], rs1 = rowstart[node + 1];
    for (int base = rs0; base < rs1; base += 256) {
        int e = base + ch;
        if (e < rs1) { lsrc[ch] = csr_src[e]; lcoef[ch] = csr_coef[e]; }
        __syncthreads();
        int m = min(256, rs1 - base);
        for (int i = 0; i < m; i++)
            acc += hw[(size_t)lsrc[i] * Hd + ch] * lcoef[i];
        __syncthreads();
    }
    acc += b_gcn[ch];
    g[(size_t)node * Hd + ch] = fmaxf(acc, 0.f);
}

// ---------------- block reduce helper ----------------
DEVINL float block_reduce_sum(float v, float* red) {
    int t = threadIdx.x;
    red[t] = v;
    __syncthreads();
    for (int off = 128; off > 0; off >>= 1) {
        if (t < off) red[t] += red[t + off];
        __syncthreads();
    }
    float r = red[0];
    __syncthreads();
    return r;
}

// ---------------- proto = mean_n t ; pn = max(||proto||, eps) ----------------
__global__ __launch_bounds__(256) void k_proto(const float* __restrict__ t,
                                               float* __restrict__ proto,
                                               float* __restrict__ pn) {
    __shared__ float red[256];
    int b = blockIdx.x, ch = threadIdx.x;
    float s = 0.f;
    for (int n = 0; n < Nn; n++) s += t[(size_t)(b * Nn + n) * Hd + ch];
    float p = s * (1.f / (float)Nn);
    proto[b * Hd + ch] = p;
    float s2 = block_reduce_sum(p * p, red);
    if (ch == 0) pn[b] = fmaxf(sqrtf(s2), 1e-8f);
}

// ---------------- per-node: att & mw scale ----------------
__global__ __launch_bounds__(256) void k_att(const float* __restrict__ t,
                                             const float* __restrict__ proto,
                                             const float* __restrict__ pn,
                                             const float* __restrict__ ew,
                                             float* __restrict__ scale) {
    __shared__ float red[256];
    int node = blockIdx.x;
    int b = node >> 9; // /512
    int ch = threadIdx.x;
    float tv = t[(size_t)node * Hd + ch];
    float pv = proto[b * Hd + ch];
    float dot = block_reduce_sum(tv * pv, red);
    float sq  = block_reduce_sum(tv * tv, red);
    float wv  = (ch < Vv) ? ew[(size_t)node * Vv + ch] : 0.f;
    float wsum = block_reduce_sum(wv, red);
    if (ch == 0) {
        float tn  = fmaxf(sqrtf(sq), 1e-8f);
        float sim = dot / (tn * pn[b]);
        float att = 0.5f * (1.f + sim);
        float rs  = att * wsum;
        float den = (rs == 0.f) ? 1.f : rs;
        scale[node] = att / den;
    }
}

// ---------------- vn[b,v,:] = sum_n (ew[b,n,v]*scale[b,n]) * g[b,n,:] ----------------
__global__ __launch_bounds__(256) void k_vn(const float* __restrict__ g,
                                            const float* __restrict__ ew,
                                            const float* __restrict__ scale,
                                            float* __restrict__ vn) {
    __shared__ float lw[256];
    int bv = blockIdx.x;
    int b = bv >> 6, v = bv & 63;
    int ch = threadIdx.x;
    float acc = 0.f;
    for (int base = 0; base < Nn; base += 256) {
        int node = b * Nn + base + ch;
        lw[ch] = scale[node] * ew[(size_t)node * Vv + v];
        __syncthreads();
        for (int i = 0; i < 256; i++)
            acc += lw[i] * g[(size_t)(b * Nn + base + i) * Hd + ch];
        __syncthreads();
    }
    vn[(size_t)bv * Hd + ch] = acc;
}

// ---------------- head: gf = mean_v vn2 ; out = relu(gf@mW1+mb1)@mW2+mb2 ----------------
__global__ __launch_bounds__(256) void k_head(const float* __restrict__ vn2,
                                              const float* __restrict__ mW1,
                                              const float* __restrict__ mb1,
                                              const float* __restrict__ mW2,
                                              const float* __restrict__ mb2,
                                              float* __restrict__ out) {
    __shared__ float gfs[256];
    __shared__ float zs[256];
    int b = blockIdx.x, t = threadIdx.x;
    float s = 0.f;
    for (int v = 0; v < Vv; v++) s += vn2[(size_t)(b * Vv + v) * Hd + t];
    gfs[t] = s * (1.f / (float)Vv);
    __syncthreads();
    float z = mb1[t];
    for (int k = 0; k < Hd; k++) z += gfs[k] * mW1[k * Hd + t];
    zs[t] = fmaxf(z, 0.f);
    __syncthreads();
    if (t < OUTD) {
        float o = mb2[t];
        for (int ch = 0; ch < Hd; ch++) o += zs[ch] * mW2[ch * OUTD + t];
        out[b * OUTD + t] = o;
    }
}

// =======================================================================
extern "C" void kernel_launch(void* const* d_in, const int* in_sizes, int n_in,
                              void* d_out, int out_size, void* d_ws, size_t ws_size,
                              hipStream_t stream) {
    const float* x     = (const float*)d_in[0];
    const int*   esrc  = (const int*)d_in[1];
    const int*   edst  = (const int*)d_in[2];
    const float* W_emb = (const float*)d_in[3];
    const float* b_emb = (const float*)d_in[4];
    const float* W_gcn = (const float*)d_in[5];
    const float* b_gcn = (const float*)d_in[6];
    const float* aW1   = (const float*)d_in[7];
    const float* ab1   = (const float*)d_in[8];
    const float* aW2   = (const float*)d_in[9];
    const float* ab2   = (const float*)d_in[10];
    const float* vW1   = (const float*)d_in[11];
    const float* vb1   = (const float*)d_in[12];
    const float* vW2   = (const float*)d_in[13];
    const float* vb2   = (const float*)d_in[14];
    const float* mW1   = (const float*)d_in[15];
    const float* mb1   = (const float*)d_in[16];
    const float* mW2   = (const float*)d_in[17];
    const float* mb2   = (const float*)d_in[18];
    const float* ew    = (const float*)d_in[19];
    float* out = (float*)d_out;

    char* w = (char*)d_ws;
    auto alloc = [&](size_t bytes) -> void* {
        void* p = (void*)w;
        w += (bytes + 255) & ~(size_t)255;
        return p;
    };
    int*   cnt      = (int*)  alloc(TOTAL_N * 4);
    int*   rowstart = (int*)  alloc((TOTAL_N + 1) * 4);
    int*   cursor   = (int*)  alloc(TOTAL_N * 4);
    float* dinv     = (float*)alloc(TOTAL_N * 4);
    int*   csr_src  = (int*)  alloc((size_t)NE * 4);
    float* csr_coef = (float*)alloc((size_t)NE * 4);
    float* buf0     = (float*)alloc((size_t)TOTAL_N * Hd * 4); // h -> g
    float* buf1     = (float*)alloc((size_t)TOTAL_N * Hd * 4); // hw -> atmp
    float* buf2     = (float*)alloc((size_t)TOTAL_N * Hd * 4); // t
    float* vn       = (float*)alloc((size_t)Bg * Vv * Hd * 4);
    float* vtmp     = (float*)alloc((size_t)Bg * Vv * Hd * 4);
    float* vn2      = (float*)alloc((size_t)Bg * Vv * Hd * 4);
    float* proto    = (float*)alloc(Bg * Hd * 4);
    float* pn       = (float*)alloc(Bg * 4);
    float* scale    = (float*)alloc(TOTAL_N * 4);

    // ---- CSR build ----
    k_zero_i32<<<(TOTAL_N + 255) / 256, 256, 0, stream>>>(cnt, TOTAL_N);
    k_count<<<NE / 256, 256, 0, stream>>>(edst, cnt);
    k_scan<<<1, 1024, 0, stream>>>(cnt, rowstart, cursor, dinv);
    k_scatter<<<NE / 256, 256, 0, stream>>>(esrc, edst, cursor, dinv, csr_src, csr_coef);

    // ---- h = x @ W_emb + b_emb ----  (buf0 = h)
    k_gemm<<<dim3(Hd / 64, TOTAL_N / 64), 256, 0, stream>>>(x, W_emb, b_emb, buf0,
                                                            TOTAL_N, IND, Hd, 0);
    // ---- hw = h @ W_gcn ----  (buf1 = hw)
    k_gemm<<<dim3(Hd / 64, TOTAL_N / 64), 256, 0, stream>>>(buf0, W_gcn, nullptr, buf1,
                                                            TOTAL_N, Hd, Hd, 0);
    // ---- g = relu(agg + b_gcn) ----  (buf0 = g; h dead)
    k_agg<<<TOTAL_N, 256, 0, stream>>>(buf1, rowstart, csr_src, csr_coef, dinv, b_gcn, buf0);

    // ---- t = relu(g@aW1+ab1)@aW2+ab2 ----  (buf1 = atmp, buf2 = t)
    k_gemm<<<dim3(Hd / 64, TOTAL_N / 64), 256, 0, stream>>>(buf0, aW1, ab1, buf1,
                                                            TOTAL_N, Hd, Hd, 1);
    k_gemm<<<dim3(Hd / 64, TOTAL_N / 64), 256, 0, stream>>>(buf1, aW2, ab2, buf2,
                                                            TOTAL_N, Hd, Hd, 0);

    // ---- proto, pn, att scale ----
    k_proto<<<Bg, 256, 0, stream>>>(buf2, proto, pn);
    k_att<<<TOTAL_N, 256, 0, stream>>>(buf2, proto, pn, ew, scale);

    // ---- vn einsum (reads g = buf0) ----
    k_vn<<<Bg * Vv, 256, 0, stream>>>(buf0, ew, scale, vn);

    // ---- vn MLP ----
    k_gemm<<<dim3(Hd / 64, (Bg * Vv) / 64), 256, 0, stream>>>(vn, vW1, vb1, vtmp,
                                                              Bg * Vv, Hd, Hd, 1);
    k_gemm<<<dim3(Hd / 64, (Bg * Vv) / 64), 256, 0, stream>>>(vtmp, vW2, vb2, vn2,
                                                              Bg * Vv, Hd, Hd, 0);

    // ---- head ----
    k_head<<<Bg, 256, 0, stream>>>(vn2, mW1, mb1, mW2, mb2, out);
}

// Round 3
// 448.259 us; speedup vs baseline: 1.6615x; 1.6615x over previous
//
#include <hip/hip_runtime.h>
#include <hip/hip_bf16.h>

#define DEVINL __device__ __forceinline__

typedef unsigned short u16;
typedef short v8s  __attribute__((ext_vector_type(8)));
typedef float v4f  __attribute__((ext_vector_type(4)));
typedef u16   v4u16 __attribute__((ext_vector_type(4)));
typedef short v4s16 __attribute__((ext_vector_type(4)));

constexpr int Bg      = 64;
constexpr int Nn      = 512;
constexpr int Vv      = 64;
constexpr int IND     = 128;
constexpr int Hd      = 256;
constexpr int OUTD    = 10;
constexpr int TOTAL_N = Bg * Nn;    // 32768
constexpr int NE      = Bg * 16384; // 1048576

DEVINL u16 f2bf(float f) {
    unsigned u = __float_as_uint(f);
    u += 0x7FFF + ((u >> 16) & 1);   // RNE
    return (u16)(u >> 16);
}
DEVINL float bf2f(u16 s) { return __uint_as_float(((unsigned)s) << 16); }

DEVINL void ld4f(const float* p, float o[4]) {
    float4 v = *(const float4*)p;
    o[0] = v.x; o[1] = v.y; o[2] = v.z; o[3] = v.w;
}
DEVINL void ld4f(const u16* p, float o[4]) {
    v4u16 v = *(const v4u16*)p;
    o[0] = bf2f(v[0]); o[1] = bf2f(v[1]); o[2] = bf2f(v[2]); o[3] = bf2f(v[3]);
}
DEVINL void stC(float* C, size_t idx, float v) { C[idx] = v; }
DEVINL void stC(u16* C, size_t idx, float v)   { C[idx] = f2bf(v); }

// ---------------- zero int buffer ----------------
__global__ void k_zero_i32(int* p, int n) {
    int i = blockIdx.x * blockDim.x + threadIdx.x;
    if (i < n) p[i] = 0;
}

// ---------------- edge count ----------------
__global__ void k_count(const int* __restrict__ edst, int* __restrict__ cnt) {
    int e = blockIdx.x * blockDim.x + threadIdx.x;
    if (e < NE) atomicAdd(&cnt[edst[e]], 1);
}

// ---------------- exclusive scan over 32768 counts ----------------
__global__ __launch_bounds__(1024) void k_scan(const int* __restrict__ cnt,
                                               int* __restrict__ rowstart,
                                               int* __restrict__ cursor,
                                               float* __restrict__ dinv) {
    __shared__ int part[1024];
    int t = threadIdx.x;
    int base = t * 32;
    int local[32];
    int s = 0;
#pragma unroll
    for (int i = 0; i < 32; i++) { local[i] = cnt[base + i]; s += local[i]; }
    part[t] = s;
    __syncthreads();
    for (int off = 1; off < 1024; off <<= 1) {
        int v = (t >= off) ? part[t - off] : 0;
        __syncthreads();
        part[t] += v;
        __syncthreads();
    }
    int run = part[t] - s;
#pragma unroll
    for (int i = 0; i < 32; i++) {
        int idx = base + i;
        rowstart[idx] = run;
        cursor[idx]   = run;
        dinv[idx] = rsqrtf((float)(local[i] + 1));
        run += local[i];
    }
    if (t == 0) rowstart[TOTAL_N] = NE;
}

// ---------------- scatter edges into CSR ----------------
__global__ void k_scatter(const int* __restrict__ esrc, const int* __restrict__ edst,
                          int* __restrict__ cursor, const float* __restrict__ dinv,
                          int* __restrict__ csr_src, float* __restrict__ csr_coef) {
    int e = blockIdx.x * blockDim.x + threadIdx.x;
    if (e >= NE) return;
    int s = esrc[e], d = edst[e];
    int pos = atomicAdd(&cursor[d], 1);
    csr_src[pos]  = s;
    csr_coef[pos] = dinv[s] * dinv[d];
}

// ---------------- weight transpose+cast: W[K][256] fp32 -> Wt[256][K] bf16 ----
struct WtArgs {
    const float* src[6];
    u16* dst[6];
    int K[6];
};
__global__ __launch_bounds__(256) void k_wt(WtArgs a) {
    int bid = blockIdx.x;
    int mi, tile;
    if (bid < 8) { mi = 0; tile = bid; }
    else { mi = 1 + (bid - 8) / 16; tile = (bid - 8) % 16; }
    int K = a.K[mi];
    int kt = K / 64;
    int k0 = (tile % kt) * 64, n0 = (tile / kt) * 64;
    const float* src = a.src[mi];
    u16* dst = a.dst[mi];
    __shared__ float T[64][65];
    int t = threadIdx.x;
#pragma unroll
    for (int j = 0; j < 16; j++) {
        int idx = t + 256 * j;
        int r = idx >> 6, c = idx & 63;       // r: k-offset, c: n-offset
        T[c][r] = src[(size_t)(k0 + r) * 256 + n0 + c];
    }
    __syncthreads();
#pragma unroll
    for (int j = 0; j < 16; j++) {
        int idx = t + 256 * j;
        int nr = idx >> 6, kc = idx & 63;
        dst[(size_t)(n0 + nr) * K + k0 + kc] = f2bf(T[nr][kc]);
    }
}

// ---------------- MFMA GEMM: C[M,256] = A[M,K] @ W[K,256] (+bias)(+relu) -----
// Wt is the bf16 transposed weight [256][K]. 128x128 tile, BK=64, 4 waves.
template <typename TA, typename TC>
__global__ __launch_bounds__(256) void k_mfma_gemm(const TA* __restrict__ A,
                                                   const u16* __restrict__ Wt,
                                                   const float* __restrict__ bias,
                                                   TC* __restrict__ C,
                                                   int M, int K, int relu) {
    constexpr int LDK = 88;  // padded k-stride (shorts): 176B rows -> 2-way bank alias (free)
    __shared__ short As[128 * LDK];
    __shared__ short Bs[128 * LDK];
    int tid  = threadIdx.x;
    int row0 = blockIdx.y * 128, col0 = blockIdx.x * 128;
    int lane = tid & 63, wid = tid >> 6;
    int wm = (wid >> 1) * 64, wn = (wid & 1) * 64;
    int q = lane >> 4, r = lane & 15;
    v4f acc[4][4];
#pragma unroll
    for (int i = 0; i < 4; i++)
#pragma unroll
        for (int j = 0; j < 4; j++) acc[i][j] = (v4f){0.f, 0.f, 0.f, 0.f};
    int sm = tid >> 1, sk = (tid & 1) * 32;
    for (int k0 = 0; k0 < K; k0 += 64) {
        const TA* ap  = A  + (size_t)(row0 + sm) * K + k0 + sk;
        const u16* bp = Wt + (size_t)(col0 + sm) * K + k0 + sk;
        short* adst = &As[sm * LDK + sk];
        short* bdst = &Bs[sm * LDK + sk];
#pragma unroll
        for (int i = 0; i < 8; i++) {
            float o[4];
            ld4f(ap + 4 * i, o);
            v4s16 pa;
            pa[0] = (short)f2bf(o[0]); pa[1] = (short)f2bf(o[1]);
            pa[2] = (short)f2bf(o[2]); pa[3] = (short)f2bf(o[3]);
            *(v4s16*)(adst + 4 * i) = pa;
            *(v4u16*)(bdst + 4 * i) = *(const v4u16*)(bp + 4 * i);
        }
        __syncthreads();
#pragma unroll
        for (int ks = 0; ks < 64; ks += 32) {
            v8s af[4], bfr[4];
#pragma unroll
            for (int i = 0; i < 4; i++)
                af[i] = *(const v8s*)&As[(wm + i * 16 + r) * LDK + ks + q * 8];
#pragma unroll
            for (int j = 0; j < 4; j++)
                bfr[j] = *(const v8s*)&Bs[(wn + j * 16 + r) * LDK + ks + q * 8];
#pragma unroll
            for (int i = 0; i < 4; i++)
#pragma unroll
                for (int j = 0; j < 4; j++)
                    acc[i][j] = __builtin_amdgcn_mfma_f32_16x16x32_bf16(af[i], bfr[j], acc[i][j], 0, 0, 0);
        }
        __syncthreads();
    }
#pragma unroll
    for (int i = 0; i < 4; i++) {
#pragma unroll
        for (int j = 0; j < 4; j++) {
            int col = col0 + wn + j * 16 + r;
            float bv = bias ? bias[col] : 0.f;
#pragma unroll
            for (int rg = 0; rg < 4; rg++) {
                int row = row0 + wm + i * 16 + q * 4 + rg;
                float v = acc[i][j][rg] + bv;
                if (relu) v = fmaxf(v, 0.f);
                stC(C, (size_t)row * 256 + col, v);
            }
        }
    }
}

// ---------------- GCN aggregation (bf16 hw in, bf16 g out) ----------------
__global__ __launch_bounds__(256) void k_agg(const u16* __restrict__ hw,
                                             const int* __restrict__ rowstart,
                                             const int* __restrict__ csr_src,
                                             const float* __restrict__ csr_coef,
                                             const float* __restrict__ dinv,
                                             const float* __restrict__ b_gcn,
                                             u16* __restrict__ g) {
    __shared__ int   lsrc[256];
    __shared__ float lcoef[256];
    // XCD-swizzle: cluster consecutive nodes (same graph) on one XCD for L2 reuse
    int node = ((blockIdx.x & 7) << 12) | (blockIdx.x >> 3);
    int ch = threadIdx.x;
    float di = dinv[node];
    float acc = bf2f(hw[(size_t)node * Hd + ch]) * di * di; // self-loop: hw/deg
    int rs0 = rowstart[node], rs1 = rowstart[node + 1];
    for (int base = rs0; base < rs1; base += 256) {
        int e = base + ch;
        if (e < rs1) { lsrc[ch] = csr_src[e]; lcoef[ch] = csr_coef[e]; }
        __syncthreads();
        int m = min(256, rs1 - base);
        for (int i = 0; i < m; i++)
            acc += bf2f(hw[(size_t)lsrc[i] * Hd + ch]) * lcoef[i];
        __syncthreads();
    }
    acc += b_gcn[ch];
    g[(size_t)node * Hd + ch] = f2bf(fmaxf(acc, 0.f));
}

// ---------------- block reduce helper ----------------
DEVINL float block_reduce_sum(float v, float* red) {
    int t = threadIdx.x;
    red[t] = v;
    __syncthreads();
    for (int off = 128; off > 0; off >>= 1) {
        if (t < off) red[t] += red[t + off];
        __syncthreads();
    }
    float r = red[0];
    __syncthreads();
    return r;
}

// ---------------- proto = mean_n t ; pn = max(||proto||, eps) ----------------
__global__ __launch_bounds__(256) void k_proto(const u16* __restrict__ t,
                                               float* __restrict__ proto,
                                               float* __restrict__ pn) {
    __shared__ float red[256];
    int b = blockIdx.x, ch = threadIdx.x;
    float s = 0.f;
    for (int n = 0; n < Nn; n++) s += bf2f(t[(size_t)(b * Nn + n) * Hd + ch]);
    float p = s * (1.f / (float)Nn);
    proto[b * Hd + ch] = p;
    float s2 = block_reduce_sum(p * p, red);
    if (ch == 0) pn[b] = fmaxf(sqrtf(s2), 1e-8f);
}

// ---------------- per-node: att & mw scale ----------------
__global__ __launch_bounds__(256) void k_att(const u16* __restrict__ t,
                                             const float* __restrict__ proto,
                                             const float* __restrict__ pn,
                                             const float* __restrict__ ew,
                                             float* __restrict__ scale) {
    __shared__ float red[256];
    int node = blockIdx.x;
    int b = node >> 9;
    int ch = threadIdx.x;
    float tv = bf2f(t[(size_t)node * Hd + ch]);
    float pv = proto[b * Hd + ch];
    float dot = block_reduce_sum(tv * pv, red);
    float sq  = block_reduce_sum(tv * tv, red);
    float wv  = (ch < Vv) ? ew[(size_t)node * Vv + ch] : 0.f;
    float wsum = block_reduce_sum(wv, red);
    if (ch == 0) {
        float tn  = fmaxf(sqrtf(sq), 1e-8f);
        float sim = dot / (tn * pn[b]);
        float att = 0.5f * (1.f + sim);
        float rs  = att * wsum;
        float den = (rs == 0.f) ? 1.f : rs;
        scale[node] = att / den;
    }
}

// ---------------- vn[b] = (ew*scale)^T @ g[b] : per-graph 64x256x512 GEMM ----
// grid (Hd/64, Bg); 256 threads; BM=64(v) BN=64(h) BK=16(n); 4x4 micro-tile.
__global__ __launch_bounds__(256) void k_vn_gemm(const float* __restrict__ ew,
                                                 const float* __restrict__ scale,
                                                 const u16* __restrict__ g,
                                                 u16* __restrict__ vn) {
    __shared__ float As[16][64];      // [n-slice][v]
    __shared__ float Ws[16][64 + 1];  // [n-slice][h]
    int b = blockIdx.y;
    int col0 = blockIdx.x * 64;
    int tid = threadIdx.x;
    int tx = tid & 15, ty = tid >> 4;
    float acc[4][4] = {};
    int kk = tid >> 4, c4 = (tid & 15) * 4;
    for (int k0 = 0; k0 < Nn; k0 += 16) {
        int n = b * Nn + k0 + kk;
        float sc = scale[n];
        float4 e = *(const float4*)&ew[(size_t)n * Vv + c4];
        As[kk][c4 + 0] = e.x * sc;
        As[kk][c4 + 1] = e.y * sc;
        As[kk][c4 + 2] = e.z * sc;
        As[kk][c4 + 3] = e.w * sc;
        v4u16 gv = *(const v4u16*)&g[(size_t)n * Hd + col0 + c4];
        Ws[kk][c4 + 0] = bf2f(gv[0]);
        Ws[kk][c4 + 1] = bf2f(gv[1]);
        Ws[kk][c4 + 2] = bf2f(gv[2]);
        Ws[kk][c4 + 3] = bf2f(gv[3]);
        __syncthreads();
#pragma unroll
        for (int k = 0; k < 16; k++) {
            float a[4], w[4];
#pragma unroll
            for (int i = 0; i < 4; i++) a[i] = As[k][ty * 4 + i];
#pragma unroll
            for (int j = 0; j < 4; j++) w[j] = Ws[k][tx * 4 + j];
#pragma unroll
            for (int i = 0; i < 4; i++)
#pragma unroll
                for (int j = 0; j < 4; j++) acc[i][j] += a[i] * w[j];
        }
        __syncthreads();
    }
#pragma unroll
    for (int i = 0; i < 4; i++)
#pragma unroll
        for (int j = 0; j < 4; j++)
            vn[(size_t)(b * Vv + ty * 4 + i) * Hd + col0 + tx * 4 + j] = f2bf(acc[i][j]);
}

// ---------------- head ----------------
__global__ __launch_bounds__(256) void k_head(const float* __restrict__ vn2,
                                              const float* __restrict__ mW1,
                                              const float* __restrict__ mb1,
                                              const float* __restrict__ mW2,
                                              const float* __restrict__ mb2,
                                              float* __restrict__ out) {
    __shared__ float gfs[256];
    __shared__ float zs[256];
    int b = blockIdx.x, t = threadIdx.x;
    float s = 0.f;
    for (int v = 0; v < Vv; v++) s += vn2[(size_t)(b * Vv + v) * Hd + t];
    gfs[t] = s * (1.f / (float)Vv);
    __syncthreads();
    float z = mb1[t];
    for (int k = 0; k < Hd; k++) z += gfs[k] * mW1[k * Hd + t];
    zs[t] = fmaxf(z, 0.f);
    __syncthreads();
    if (t < OUTD) {
        float o = mb2[t];
        for (int ch = 0; ch < Hd; ch++) o += zs[ch] * mW2[ch * OUTD + t];
        out[b * OUTD + t] = o;
    }
}

// =======================================================================
extern "C" void kernel_launch(void* const* d_in, const int* in_sizes, int n_in,
                              void* d_out, int out_size, void* d_ws, size_t ws_size,
                              hipStream_t stream) {
    const float* x     = (const float*)d_in[0];
    const int*   esrc  = (const int*)d_in[1];
    const int*   edst  = (const int*)d_in[2];
    const float* W_emb = (const float*)d_in[3];
    const float* b_emb = (const float*)d_in[4];
    const float* W_gcn = (const float*)d_in[5];
    const float* b_gcn = (const float*)d_in[6];
    const float* aW1   = (const float*)d_in[7];
    const float* ab1   = (const float*)d_in[8];
    const float* aW2   = (const float*)d_in[9];
    const float* ab2   = (const float*)d_in[10];
    const float* vW1   = (const float*)d_in[11];
    const float* vb1   = (const float*)d_in[12];
    const float* vW2   = (const float*)d_in[13];
    const float* vb2   = (const float*)d_in[14];
    const float* mW1   = (const float*)d_in[15];
    const float* mb1   = (const float*)d_in[16];
    const float* mW2   = (const float*)d_in[17];
    const float* mb2   = (const float*)d_in[18];
    const float* ew    = (const float*)d_in[19];
    float* out = (float*)d_out;

    char* w = (char*)d_ws;
    auto alloc = [&](size_t bytes) -> void* {
        void* p = (void*)w;
        w += (bytes + 255) & ~(size_t)255;
        return p;
    };
    int*   cnt      = (int*)  alloc(TOTAL_N * 4);
    int*   rowstart = (int*)  alloc((TOTAL_N + 1) * 4);
    int*   cursor   = (int*)  alloc(TOTAL_N * 4);
    float* dinv     = (float*)alloc(TOTAL_N * 4);
    int*   csr_src  = (int*)  alloc((size_t)NE * 4);
    float* csr_coef = (float*)alloc((size_t)NE * 4);
    u16*   h_bf     = (u16*)  alloc((size_t)TOTAL_N * Hd * 2);
    u16*   hw_bf    = (u16*)  alloc((size_t)TOTAL_N * Hd * 2);
    u16*   g_bf     = (u16*)  alloc((size_t)TOTAL_N * Hd * 2);
    u16*   t1_bf    = (u16*)  alloc((size_t)TOTAL_N * Hd * 2);
    u16*   t_bf     = (u16*)  alloc((size_t)TOTAL_N * Hd * 2);
    u16*   vn_bf    = (u16*)  alloc((size_t)Bg * Vv * Hd * 2);
    u16*   vtmp_bf  = (u16*)  alloc((size_t)Bg * Vv * Hd * 2);
    float* vn2      = (float*)alloc((size_t)Bg * Vv * Hd * 4);
    float* proto    = (float*)alloc(Bg * Hd * 4);
    float* pn       = (float*)alloc(Bg * 4);
    float* scale    = (float*)alloc(TOTAL_N * 4);
    u16*   wt_emb   = (u16*)  alloc((size_t)Hd * IND * 2);
    u16*   wt_gcn   = (u16*)  alloc((size_t)Hd * Hd * 2);
    u16*   wt_a1    = (u16*)  alloc((size_t)Hd * Hd * 2);
    u16*   wt_a2    = (u16*)  alloc((size_t)Hd * Hd * 2);
    u16*   wt_v1    = (u16*)  alloc((size_t)Hd * Hd * 2);
    u16*   wt_v2    = (u16*)  alloc((size_t)Hd * Hd * 2);

    // ---- weight transpose+cast (independent of everything else) ----
    WtArgs wa;
    wa.src[0] = W_emb; wa.dst[0] = wt_emb; wa.K[0] = IND;
    wa.src[1] = W_gcn; wa.dst[1] = wt_gcn; wa.K[1] = Hd;
    wa.src[2] = aW1;   wa.dst[2] = wt_a1;  wa.K[2] = Hd;
    wa.src[3] = aW2;   wa.dst[3] = wt_a2;  wa.K[3] = Hd;
    wa.src[4] = vW1;   wa.dst[4] = wt_v1;  wa.K[4] = Hd;
    wa.src[5] = vW2;   wa.dst[5] = wt_v2;  wa.K[5] = Hd;
    k_wt<<<88, 256, 0, stream>>>(wa);

    // ---- CSR build ----
    k_zero_i32<<<(TOTAL_N + 255) / 256, 256, 0, stream>>>(cnt, TOTAL_N);
    k_count<<<NE / 256, 256, 0, stream>>>(edst, cnt);
    k_scan<<<1, 1024, 0, stream>>>(cnt, rowstart, cursor, dinv);
    k_scatter<<<NE / 256, 256, 0, stream>>>(esrc, edst, cursor, dinv, csr_src, csr_coef);

    // ---- h = x @ W_emb + b_emb ----
    k_mfma_gemm<float, u16><<<dim3(2, TOTAL_N / 128), 256, 0, stream>>>(
        x, wt_emb, b_emb, h_bf, TOTAL_N, IND, 0);
    // ---- hw = h @ W_gcn ----
    k_mfma_gemm<u16, u16><<<dim3(2, TOTAL_N / 128), 256, 0, stream>>>(
        h_bf, wt_gcn, nullptr, hw_bf, TOTAL_N, Hd, 0);
    // ---- g = relu(agg + b_gcn) ----
    k_agg<<<TOTAL_N, 256, 0, stream>>>(hw_bf, rowstart, csr_src, csr_coef, dinv, b_gcn, g_bf);

    // ---- t = relu(g@aW1+ab1)@aW2+ab2 ----
    k_mfma_gemm<u16, u16><<<dim3(2, TOTAL_N / 128), 256, 0, stream>>>(
        g_bf, wt_a1, ab1, t1_bf, TOTAL_N, Hd, 1);
    k_mfma_gemm<u16, u16><<<dim3(2, TOTAL_N / 128), 256, 0, stream>>>(
        t1_bf, wt_a2, ab2, t_bf, TOTAL_N, Hd, 0);

    // ---- proto, pn, att scale ----
    k_proto<<<Bg, 256, 0, stream>>>(t_bf, proto, pn);
    k_att<<<TOTAL_N, 256, 0, stream>>>(t_bf, proto, pn, ew, scale);

    // ---- vn = (ew*scale)^T @ g per graph ----
    k_vn_gemm<<<dim3(Hd / 64, Bg), 256, 0, stream>>>(ew, scale, g_bf, vn_bf);

    // ---- vn MLP ----
    k_mfma_gemm<u16, u16><<<dim3(2, (Bg * Vv) / 128), 256, 0, stream>>>(
        vn_bf, wt_v1, vb1, vtmp_bf, Bg * Vv, Hd, 1);
    k_mfma_gemm<u16, float><<<dim3(2, (Bg * Vv) / 128), 256, 0, stream>>>(
        vtmp_bf, wt_v2, vb2, vn2, Bg * Vv, Hd, 0);

    // ---- head ----
    k_head<<<Bg, 256, 0, stream>>>(vn2, mW1, mb1, mW2, mb2, out);
}

// Round 4
// 378.324 us; speedup vs baseline: 1.9687x; 1.1849x over previous
//
#include <hip/hip_runtime.h>
#include <hip/hip_bf16.h>

#define DEVINL __device__ __forceinline__

typedef unsigned short u16;
typedef short v8s   __attribute__((ext_vector_type(8)));
typedef float v4f   __attribute__((ext_vector_type(4)));
typedef u16   v4u16 __attribute__((ext_vector_type(4)));
typedef short v4s16 __attribute__((ext_vector_type(4)));

constexpr int Bg      = 64;
constexpr int Nn      = 512;
constexpr int Vv      = 64;
constexpr int IND     = 128;
constexpr int Hd      = 256;
constexpr int OUTD    = 10;
constexpr int TOTAL_N = Bg * Nn;    // 32768
constexpr int NE      = Bg * 16384; // 1048576

DEVINL u16 f2bf(float f) {
    unsigned u = __float_as_uint(f);
    u += 0x7FFF + ((u >> 16) & 1);   // RNE
    return (u16)(u >> 16);
}
DEVINL float bf2f(u16 s) { return __uint_as_float(((unsigned)s) << 16); }

DEVINL void ld4f(const float* p, float o[4]) {
    float4 v = *(const float4*)p;
    o[0] = v.x; o[1] = v.y; o[2] = v.z; o[3] = v.w;
}
DEVINL void ld4f(const u16* p, float o[4]) {
    v4u16 v = *(const v4u16*)p;
    o[0] = bf2f(v[0]); o[1] = bf2f(v[1]); o[2] = bf2f(v[2]); o[3] = bf2f(v[3]);
}
DEVINL void stC(float* C, size_t idx, float v) { C[idx] = v; }
DEVINL void stC(u16* C, size_t idx, float v)   { C[idx] = f2bf(v); }

// ---------------- zero int buffer ----------------
__global__ void k_zero_i32(int* p, int n) {
    int i = blockIdx.x * blockDim.x + threadIdx.x;
    if (i < n) p[i] = 0;
}

// ---------------- edge count ----------------
__global__ void k_count(const int* __restrict__ edst, int* __restrict__ cnt) {
    int e = blockIdx.x * blockDim.x + threadIdx.x;
    if (e < NE) atomicAdd(&cnt[edst[e]], 1);
}

// ---------------- exclusive scan over 32768 counts ----------------
__global__ __launch_bounds__(1024) void k_scan(const int* __restrict__ cnt,
                                               int* __restrict__ rowstart,
                                               int* __restrict__ cursor,
                                               float* __restrict__ dinv) {
    __shared__ int part[1024];
    int t = threadIdx.x;
    int base = t * 32;
    int local[32];
    int s = 0;
#pragma unroll
    for (int i = 0; i < 32; i++) { local[i] = cnt[base + i]; s += local[i]; }
    part[t] = s;
    __syncthreads();
    for (int off = 1; off < 1024; off <<= 1) {
        int v = (t >= off) ? part[t - off] : 0;
        __syncthreads();
        part[t] += v;
        __syncthreads();
    }
    int run = part[t] - s;
#pragma unroll
    for (int i = 0; i < 32; i++) {
        int idx = base + i;
        rowstart[idx] = run;
        cursor[idx]   = run;
        dinv[idx] = rsqrtf((float)(local[i] + 1));
        run += local[i];
    }
    if (t == 0) rowstart[TOTAL_N] = NE;
}

// ---------------- scatter edges into CSR ----------------
__global__ void k_scatter(const int* __restrict__ esrc, const int* __restrict__ edst,
                          int* __restrict__ cursor, const float* __restrict__ dinv,
                          int* __restrict__ csr_src, float* __restrict__ csr_coef) {
    int e = blockIdx.x * blockDim.x + threadIdx.x;
    if (e >= NE) return;
    int s = esrc[e], d = edst[e];
    int pos = atomicAdd(&cursor[d], 1);
    csr_src[pos]  = s;
    csr_coef[pos] = dinv[s] * dinv[d];
}

// ---------------- weight transpose+cast: W[256][256] fp32 -> Wt[256][256] bf16 ----
struct WtArgs {
    const float* src[5];
    u16* dst[5];
};
__global__ __launch_bounds__(256) void k_wt(WtArgs a) {
    int bid = blockIdx.x;
    int mi = bid / 16, tile = bid % 16;
    int k0 = (tile & 3) * 64, n0 = (tile >> 2) * 64;
    const float* src = a.src[mi];
    u16* dst = a.dst[mi];
    __shared__ float T[64][65];
    int t = threadIdx.x;
#pragma unroll
    for (int j = 0; j < 16; j++) {
        int idx = t + 256 * j;
        int r = idx >> 6, c = idx & 63;       // r: k-offset, c: n-offset
        T[c][r] = src[(size_t)(k0 + r) * 256 + n0 + c];
    }
    __syncthreads();
#pragma unroll
    for (int j = 0; j < 16; j++) {
        int idx = t + 256 * j;
        int nr = idx >> 6, kc = idx & 63;
        dst[(size_t)(n0 + nr) * 256 + k0 + kc] = f2bf(T[nr][kc]);
    }
}

// ---------------- b12 = b_emb @ W_gcn (fp32) ----------------
__global__ __launch_bounds__(256) void k_b12(const float* __restrict__ b_emb,
                                             const float* __restrict__ W_gcn,
                                             float* __restrict__ b12) {
    int t = threadIdx.x;
    float acc = 0.f;
    for (int k = 0; k < IND; k++) acc += b_emb[k] * W_gcn[(size_t)k * 256 + t];
    b12[t] = acc;
}

// ---------------- MFMA GEMM: C[M,256] = A[M,K] @ W[K,256] epilogues ------------
// Wt: bf16 transposed weight [256][K]. 128x128 tile, BK=64, 4 waves.
// epilogue: v = acc + bias[col] + srow[row]*b12v[col]; optional relu.
// tstore: store transposed (C[col*M+row]) for weight-composition GEMM.
template <typename TA, typename TC>
__global__ __launch_bounds__(256) void k_mfma_gemm(const TA* __restrict__ A,
                                                   const u16* __restrict__ Wt,
                                                   const float* __restrict__ bias,
                                                   const float* __restrict__ srow,
                                                   const float* __restrict__ b12v,
                                                   TC* __restrict__ C,
                                                   int M, int K, int relu, int tstore) {
    constexpr int LDK = 88;  // padded k-stride (shorts): 176B rows -> 2-way alias (free)
    __shared__ short As[128 * LDK];
    __shared__ short Bs[128 * LDK];
    int tid  = threadIdx.x;
    int row0 = blockIdx.y * 128, col0 = blockIdx.x * 128;
    int lane = tid & 63, wid = tid >> 6;
    int wm = (wid >> 1) * 64, wn = (wid & 1) * 64;
    int q = lane >> 4, r = lane & 15;
    v4f acc[4][4];
#pragma unroll
    for (int i = 0; i < 4; i++)
#pragma unroll
        for (int j = 0; j < 4; j++) acc[i][j] = (v4f){0.f, 0.f, 0.f, 0.f};
    int sm = tid >> 1, sk = (tid & 1) * 32;
    for (int k0 = 0; k0 < K; k0 += 64) {
        const TA* ap  = A  + (size_t)(row0 + sm) * K + k0 + sk;
        const u16* bp = Wt + (size_t)(col0 + sm) * K + k0 + sk;
        short* adst = &As[sm * LDK + sk];
        short* bdst = &Bs[sm * LDK + sk];
#pragma unroll
        for (int i = 0; i < 8; i++) {
            float o[4];
            ld4f(ap + 4 * i, o);
            v4s16 pa;
            pa[0] = (short)f2bf(o[0]); pa[1] = (short)f2bf(o[1]);
            pa[2] = (short)f2bf(o[2]); pa[3] = (short)f2bf(o[3]);
            *(v4s16*)(adst + 4 * i) = pa;
            *(v4u16*)(bdst + 4 * i) = *(const v4u16*)(bp + 4 * i);
        }
        __syncthreads();
#pragma unroll
        for (int ks = 0; ks < 64; ks += 32) {
            v8s af[4], bfr[4];
#pragma unroll
            for (int i = 0; i < 4; i++)
                af[i] = *(const v8s*)&As[(wm + i * 16 + r) * LDK + ks + q * 8];
#pragma unroll
            for (int j = 0; j < 4; j++)
                bfr[j] = *(const v8s*)&Bs[(wn + j * 16 + r) * LDK + ks + q * 8];
#pragma unroll
            for (int i = 0; i < 4; i++)
#pragma unroll
                for (int j = 0; j < 4; j++)
                    acc[i][j] = __builtin_amdgcn_mfma_f32_16x16x32_bf16(af[i], bfr[j], acc[i][j], 0, 0, 0);
        }
        __syncthreads();
    }
#pragma unroll
    for (int i = 0; i < 4; i++) {
#pragma unroll
        for (int j = 0; j < 4; j++) {
            int col = col0 + wn + j * 16 + r;
            float bcol = bias ? bias[col] : 0.f;
            float b12c = b12v ? b12v[col] : 0.f;
#pragma unroll
            for (int rg = 0; rg < 4; rg++) {
                int row = row0 + wm + i * 16 + q * 4 + rg;
                float v = acc[i][j][rg] + bcol;
                if (srow) v += srow[row] * b12c;
                if (relu) v = fmaxf(v, 0.f);
                if (tstore) stC(C, (size_t)col * M + row, v);
                else        stC(C, (size_t)row * 256 + col, v);
            }
        }
    }
}

// ---------------- aggregate x: xa = A_norm@x + x/deg ; s = row-sum -------------
__global__ __launch_bounds__(128) void k_aggx(const float* __restrict__ x,
                                              const int* __restrict__ rowstart,
                                              const int* __restrict__ csr_src,
                                              const float* __restrict__ csr_coef,
                                              const float* __restrict__ dinv,
                                              float* __restrict__ xa,
                                              float* __restrict__ s) {
    __shared__ int   lsrc[128];
    __shared__ float lcoef[128];
    // XCD-swizzle: cluster consecutive nodes (same graphs) per XCD for L2 reuse
    int node = ((blockIdx.x & 7) << 12) | (blockIdx.x >> 3);
    int ch = threadIdx.x;
    float di = dinv[node];
    float invdeg = di * di;
    float acc = x[(size_t)node * IND + ch] * invdeg;
    float ssum = invdeg;
    int rs0 = rowstart[node], rs1 = rowstart[node + 1];
    for (int base = rs0; base < rs1; base += 128) {
        int e = base + ch;
        if (e < rs1) { lsrc[ch] = csr_src[e]; lcoef[ch] = csr_coef[e]; }
        __syncthreads();
        int m = min(128, rs1 - base);
        for (int i = 0; i < m; i++) {
            float c = lcoef[i];
            acc += x[(size_t)lsrc[i] * IND + ch] * c;
            ssum += c;
        }
        __syncthreads();
    }
    xa[(size_t)node * IND + ch] = acc;
    if (ch == 0) s[node] = ssum;
}

// ---------------- proto = mean_n t ; pn = max(||proto||, eps) ----------------
__global__ __launch_bounds__(1024) void k_proto(const u16* __restrict__ t,
                                                float* __restrict__ proto,
                                                float* __restrict__ pn) {
    __shared__ float part[4][256];
    __shared__ float red[256];
    int b = blockIdx.x;
    int tid = threadIdx.x;
    int st = tid >> 8, ch = tid & 255;
    float sm = 0.f;
    int n0 = st * 128;
    for (int n = n0; n < n0 + 128; n++)
        sm += bf2f(t[(size_t)(b * Nn + n) * Hd + ch]);
    part[st][ch] = sm;
    __syncthreads();
    if (tid < 256) {
        float p = (part[0][ch] + part[1][ch] + part[2][ch] + part[3][ch]) * (1.f / (float)Nn);
        proto[b * Hd + ch] = p;
        red[ch] = p * p;
    }
    __syncthreads();
    for (int off = 128; off > 0; off >>= 1) {
        if (tid < off) red[tid] += red[tid + off];
        __syncthreads();
    }
    if (tid == 0) pn[b] = fmaxf(sqrtf(red[0]), 1e-8f);
}

// ---------------- per-node att & mw scale (one wave per node) ----------------
__global__ __launch_bounds__(256) void k_att(const u16* __restrict__ t,
                                             const float* __restrict__ proto,
                                             const float* __restrict__ pn,
                                             const float* __restrict__ ew,
                                             float* __restrict__ scale) {
    int tid = tid = threadIdx.x;
    int lane = tid & 63, widx = tid >> 6;
    int node = blockIdx.x * 4 + widx;
    int b = node >> 9;
    v4u16 tv4 = *(const v4u16*)&t[(size_t)node * Hd + lane * 4];
    float4 pv4 = *(const float4*)&proto[b * Hd + lane * 4];
    float t0 = bf2f(tv4[0]), t1 = bf2f(tv4[1]), t2 = bf2f(tv4[2]), t3 = bf2f(tv4[3]);
    float dot = t0 * pv4.x + t1 * pv4.y + t2 * pv4.z + t3 * pv4.w;
    float sq  = t0 * t0 + t1 * t1 + t2 * t2 + t3 * t3;
    float wv  = ew[(size_t)node * Vv + lane];
#pragma unroll
    for (int off = 32; off > 0; off >>= 1) {
        dot += __shfl_xor(dot, off);
        sq  += __shfl_xor(sq, off);
        wv  += __shfl_xor(wv, off);
    }
    if (lane == 0) {
        float tn  = fmaxf(sqrtf(sq), 1e-8f);
        float sim = dot / (tn * pn[b]);
        float att = 0.5f * (1.f + sim);
        float rs  = att * wv;
        float den = (rs == 0.f) ? 1.f : rs;
        scale[node] = att / den;
    }
}

// ---------------- vn[b] = (ew*scale)^T @ g[b] : per-graph MFMA GEMM ----------
// grid(64 graphs), 256 thr (4 waves, each owns a 64-wide h-chunk). M=64(v) K=512(n).
constexpr int LDV = 36; // padded n-stride in shorts (72B rows: 2-way alias free, 8B aligned)
DEVINL v8s ld_frag36(const short* p) {
    v4s16 lo = *(const v4s16*)p;
    v4s16 hi = *(const v4s16*)(p + 4);
    v8s f;
    f[0] = lo[0]; f[1] = lo[1]; f[2] = lo[2]; f[3] = lo[3];
    f[4] = hi[0]; f[5] = hi[1]; f[6] = hi[2]; f[7] = hi[3];
    return f;
}
__global__ __launch_bounds__(256) void k_vn_mfma(const float* __restrict__ ew,
                                                 const float* __restrict__ scale,
                                                 const u16* __restrict__ g,
                                                 u16* __restrict__ vn) {
    __shared__ short As[64 * LDV];    // [v][n]
    __shared__ short Bs[256 * LDV];   // [h][n] (transposed g tile)
    int b = blockIdx.x;
    int tid = threadIdx.x;
    int lane = tid & 63, wid = tid >> 6;
    int h0 = wid * 64;
    int q = lane >> 4, r = lane & 15;
    v4f acc[4][4];
#pragma unroll
    for (int i = 0; i < 4; i++)
#pragma unroll
        for (int j = 0; j < 4; j++) acc[i][j] = (v4f){0.f, 0.f, 0.f, 0.f};
    for (int k0 = 0; k0 < Nn; k0 += 32) {
        // stage A: mwT[v][nl] = ew[n][v]*scale[n], 64x32 elems
#pragma unroll
        for (int p = 0; p < 8; p++) {
            int e = tid + 256 * p;
            int nl = e >> 6, v = e & 63;
            int n = b * Nn + k0 + nl;
            As[v * LDV + nl] = (short)f2bf(ew[(size_t)n * Vv + v] * scale[n]);
        }
        // stage B: gT[h][nl], 32x256 elems; column loads -> b64 LDS rows
#pragma unroll
        for (int p = 0; p < 8; p++) {
            int e = tid + 256 * p;            // 0..2047
            int h = e & 255, kgrp = e >> 8;   // kgrp 0..7
            int kl = kgrp * 4;
            v4s16 tmp;
#pragma unroll
            for (int c = 0; c < 4; c++)
                tmp[c] = (short)g[(size_t)(b * Nn + k0 + kl + c) * Hd + h];
            *(v4s16*)&Bs[h * LDV + kl] = tmp;
        }
        __syncthreads();
        v8s af[4], bfr[4];
#pragma unroll
        for (int i = 0; i < 4; i++)
            af[i] = ld_frag36(&As[(i * 16 + r) * LDV + q * 8]);
#pragma unroll
        for (int j = 0; j < 4; j++)
            bfr[j] = ld_frag36(&Bs[(h0 + j * 16 + r) * LDV + q * 8]);
#pragma unroll
        for (int i = 0; i < 4; i++)
#pragma unroll
            for (int j = 0; j < 4; j++)
                acc[i][j] = __builtin_amdgcn_mfma_f32_16x16x32_bf16(af[i], bfr[j], acc[i][j], 0, 0, 0);
        __syncthreads();
    }
#pragma unroll
    for (int i = 0; i < 4; i++)
#pragma unroll
        for (int j = 0; j < 4; j++) {
            int col = h0 + j * 16 + r;
#pragma unroll
            for (int rg = 0; rg < 4; rg++) {
                int v = i * 16 + q * 4 + rg;
                vn[(size_t)(b * Vv + v) * Hd + col] = f2bf(acc[i][j][rg]);
            }
        }
}

// ---------------- head: gf = mean_v vn2 ; out = relu(gf@mW1+mb1)@mW2+mb2 ------
__global__ __launch_bounds__(256) void k_head(const float* __restrict__ vn2,
                                              const float* __restrict__ mW1,
                                              const float* __restrict__ mb1,
                                              const float* __restrict__ mW2,
                                              const float* __restrict__ mb2,
                                              float* __restrict__ out) {
    __shared__ float gfs[256];
    __shared__ float zs[256];
    int b = blockIdx.x, t = threadIdx.x;
    float s = 0.f;
    for (int v = 0; v < Vv; v++) s += vn2[(size_t)(b * Vv + v) * Hd + t];
    gfs[t] = s * (1.f / (float)Vv);
    __syncthreads();
    float z = mb1[t];
    for (int k = 0; k < Hd; k++) z += gfs[k] * mW1[k * Hd + t];
    zs[t] = fmaxf(z, 0.f);
    __syncthreads();
    if (t < OUTD) {
        float o = mb2[t];
        for (int ch = 0; ch < Hd; ch++) o += zs[ch] * mW2[ch * OUTD + t];
        out[b * OUTD + t] = o;
    }
}

// =======================================================================
extern "C" void kernel_launch(void* const* d_in, const int* in_sizes, int n_in,
                              void* d_out, int out_size, void* d_ws, size_t ws_size,
                              hipStream_t stream) {
    const float* x     = (const float*)d_in[0];
    const int*   esrc  = (const int*)d_in[1];
    const int*   edst  = (const int*)d_in[2];
    const float* W_emb = (const float*)d_in[3];
    const float* b_emb = (const float*)d_in[4];
    const float* W_gcn = (const float*)d_in[5];
    const float* b_gcn = (const float*)d_in[6];
    const float* aW1   = (const float*)d_in[7];
    const float* ab1   = (const float*)d_in[8];
    const float* aW2   = (const float*)d_in[9];
    const float* ab2   = (const float*)d_in[10];
    const float* vW1   = (const float*)d_in[11];
    const float* vb1   = (const float*)d_in[12];
    const float* vW2   = (const float*)d_in[13];
    const float* vb2   = (const float*)d_in[14];
    const float* mW1   = (const float*)d_in[15];
    const float* mb1   = (const float*)d_in[16];
    const float* mW2   = (const float*)d_in[17];
    const float* mb2   = (const float*)d_in[18];
    const float* ew    = (const float*)d_in[19];
    float* out = (float*)d_out;

    char* w = (char*)d_ws;
    auto alloc = [&](size_t bytes) -> void* {
        void* p = (void*)w;
        w += (bytes + 255) & ~(size_t)255;
        return p;
    };
    int*   cnt      = (int*)  alloc(TOTAL_N * 4);
    int*   rowstart = (int*)  alloc((TOTAL_N + 1) * 4);
    int*   cursor   = (int*)  alloc(TOTAL_N * 4);
    float* dinv     = (float*)alloc(TOTAL_N * 4);
    int*   csr_src  = (int*)  alloc((size_t)NE * 4);
    float* csr_coef = (float*)alloc((size_t)NE * 4);
    float* xa       = (float*)alloc((size_t)TOTAL_N * IND * 4);
    float* srow     = (float*)alloc(TOTAL_N * 4);
    u16*   g_bf     = (u16*)  alloc((size_t)TOTAL_N * Hd * 2);
    u16*   t1_bf    = (u16*)  alloc((size_t)TOTAL_N * Hd * 2);
    u16*   t_bf     = (u16*)  alloc((size_t)TOTAL_N * Hd * 2);
    u16*   vn_bf    = (u16*)  alloc((size_t)Bg * Vv * Hd * 2);
    u16*   vtmp_bf  = (u16*)  alloc((size_t)Bg * Vv * Hd * 2);
    float* vn2      = (float*)alloc((size_t)Bg * Vv * Hd * 4);
    float* proto    = (float*)alloc(Bg * Hd * 4);
    float* pn       = (float*)alloc(Bg * 4);
    float* scale    = (float*)alloc(TOTAL_N * 4);
    float* b12      = (float*)alloc(Hd * 4);
    u16*   wt_gcn   = (u16*)  alloc((size_t)Hd * Hd * 2);
    u16*   wt_a1    = (u16*)  alloc((size_t)Hd * Hd * 2);
    u16*   wt_a2    = (u16*)  alloc((size_t)Hd * Hd * 2);
    u16*   wt_v1    = (u16*)  alloc((size_t)Hd * Hd * 2);
    u16*   wt_v2    = (u16*)  alloc((size_t)Hd * Hd * 2);
    u16*   wt_12    = (u16*)  alloc((size_t)Hd * IND * 2);  // (W_emb@W_gcn)^T bf16

    // ---- weight transpose+cast ----
    WtArgs wa;
    wa.src[0] = W_gcn; wa.dst[0] = wt_gcn;
    wa.src[1] = aW1;   wa.dst[1] = wt_a1;
    wa.src[2] = aW2;   wa.dst[2] = wt_a2;
    wa.src[3] = vW1;   wa.dst[3] = wt_v1;
    wa.src[4] = vW2;   wa.dst[4] = wt_v2;
    k_wt<<<80, 256, 0, stream>>>(wa);

    // ---- composite weight: wt_12 = (W_emb @ W_gcn)^T via MFMA, transposed store ----
    k_mfma_gemm<float, u16><<<dim3(2, 1), 256, 0, stream>>>(
        W_emb, wt_gcn, nullptr, nullptr, nullptr, wt_12, IND, Hd, 0, 1);
    k_b12<<<1, 256, 0, stream>>>(b_emb, W_gcn, b12);

    // ---- CSR build ----
    k_zero_i32<<<(TOTAL_N + 255) / 256, 256, 0, stream>>>(cnt, TOTAL_N);
    k_count<<<NE / 256, 256, 0, stream>>>(edst, cnt);
    k_scan<<<1, 1024, 0, stream>>>(cnt, rowstart, cursor, dinv);
    k_scatter<<<NE / 256, 256, 0, stream>>>(esrc, edst, cursor, dinv, csr_src, csr_coef);

    // ---- xa = A_norm@x + x/deg ; srow ----
    k_aggx<<<TOTAL_N, 128, 0, stream>>>(x, rowstart, csr_src, csr_coef, dinv, xa, srow);

    // ---- g = relu(xa@W12 + srow*b12 + b_gcn) ----
    k_mfma_gemm<float, u16><<<dim3(2, TOTAL_N / 128), 256, 0, stream>>>(
        xa, wt_12, b_gcn, srow, b12, g_bf, TOTAL_N, IND, 1, 0);

    // ---- t = relu(g@aW1+ab1)@aW2+ab2 ----
    k_mfma_gemm<u16, u16><<<dim3(2, TOTAL_N / 128), 256, 0, stream>>>(
        g_bf, wt_a1, ab1, nullptr, nullptr, t1_bf, TOTAL_N, Hd, 1, 0);
    k_mfma_gemm<u16, u16><<<dim3(2, TOTAL_N / 128), 256, 0, stream>>>(
        t1_bf, wt_a2, ab2, nullptr, nullptr, t_bf, TOTAL_N, Hd, 0, 0);

    // ---- proto, pn, att scale ----
    k_proto<<<Bg, 1024, 0, stream>>>(t_bf, proto, pn);
    k_att<<<TOTAL_N / 4, 256, 0, stream>>>(t_bf, proto, pn, ew, scale);

    // ---- vn = (ew*scale)^T @ g per graph (MFMA) ----
    k_vn_mfma<<<Bg, 256, 0, stream>>>(ew, scale, g_bf, vn_bf);

    // ---- vn MLP ----
    k_mfma_gemm<u16, u16><<<dim3(2, (Bg * Vv) / 128), 256, 0, stream>>>(
        vn_bf, wt_v1, vb1, nullptr, nullptr, vtmp_bf, Bg * Vv, Hd, 1, 0);
    k_mfma_gemm<u16, float><<<dim3(2, (Bg * Vv) / 128), 256, 0, stream>>>(
        vtmp_bf, wt_v2, vb2, nullptr, nullptr, vn2, Bg * Vv, Hd, 0, 0);

    // ---- head ----
    k_head<<<Bg, 256, 0, stream>>>(vn2, mW1, mb1, mW2, mb2, out);
}